// Round 13
// baseline (101.007 us; speedup 1.0000x reference)
//
#include <hip/hip_runtime.h>
#include <hip/hip_bf16.h>
#include <stdint.h>

typedef __attribute__((ext_vector_type(8))) short bf16x8;
typedef __attribute__((ext_vector_type(4))) float f32x4;

#define NPOS 256
#define NROW 512
#define NCH  256
#define PSTRIDE 262144   // bytes per position panel: 512 rows * 256 ch * 2B

// ---------------------------------------------------------------------------
// Kernel 1: repack fp32 [i][c][p] -> bf16 X[p][i][c]  (LDS tile transpose)
// + fused SQ partials (no atomics). r8-proven version (best timed total).
// grid: 512 i * 4 cb * 4 pb = 8192 blocks, 256 threads.
// ---------------------------------------------------------------------------
__global__ __launch_bounds__(256) void k_repack(const float* __restrict__ src,
                                                const float* __restrict__ tgt,
                                                unsigned short* __restrict__ X,
                                                float* __restrict__ SQP) {
  __shared__ float tile[64 * 65];  // [c][p], +1 pad
  int bx = blockIdx.x;
  int i  = bx >> 4;
  int cb = (bx >> 2) & 3;
  int pb = bx & 3;
  int c0 = cb * 64, p0 = pb * 64;
  const float* base = (i < 256) ? (src + (size_t)i * 65536)
                                : (tgt + (size_t)(i - 256) * 65536);
  int t = threadIdx.x;
#pragma unroll
  for (int it = 0; it < 4; ++it) {
    int idx = it * 256 + t;
    int cl = idx >> 4, pq = idx & 15;                // float4 along p (coalesced)
    float4 v = *(const float4*)&base[(c0 + cl) * 256 + p0 + pq * 4];
    tile[cl * 65 + pq * 4 + 0] = v.x;
    tile[cl * 65 + pq * 4 + 1] = v.y;
    tile[cl * 65 + pq * 4 + 2] = v.z;
    tile[cl * 65 + pq * 4 + 3] = v.w;
  }
  __syncthreads();
#pragma unroll
  for (int it = 0; it < 2; ++it) {
    int idx = it * 256 + t;
    int pl = idx >> 3, c8 = idx & 7;                 // 8 threads per p-row
    unsigned rr[8];
    float part = 0.f;
#pragma unroll
    for (int j = 0; j < 8; ++j) {
      unsigned u = __float_as_uint(tile[(c8 * 8 + j) * 65 + pl]);
      rr[j] = (u + 0x7fffu + ((u >> 16) & 1u)) >> 16;        // RNE to bf16
      float fr = __uint_as_float(rr[j] << 16);               // square ROUNDED value
      part += fr * fr;
    }
    uint4 o = { rr[0] | (rr[1] << 16), rr[2] | (rr[3] << 16),
                rr[4] | (rr[5] << 16), rr[6] | (rr[7] << 16) };
    *(uint4*)&X[((size_t)(p0 + pl) * NROW + i) * NCH + c0 + c8 * 8] = o;
    part += __shfl_xor(part, 1, 64);
    part += __shfl_xor(part, 2, 64);
    part += __shfl_xor(part, 4, 64);
    if (c8 == 0)
      SQP[(size_t)cb * (NPOS * NROW) + (size_t)(p0 + pl) * NROW + i] = part;
  }
}

// ---------------------------------------------------------------------------
// Kernel 2: fused Gram + RBF-sum epilogue, FULL-K-PANEL staging.
// As/Bs = 128 rows x 256 ch bf16 (64 KB each, 128 KB total): the whole K=256
// staged ONCE -> one vmcnt(0) drain per block instead of 4. Compute phase is
// barrier-free: 8 x {6 ds_read_b128 + 16 MFMA} per wave, lgkm-pipelined.
// 8 waves (512 thr), wave w -> (r=w>>1,c=w&1): 32x64 subtile.
// Staging: wave-uniform LDS dest (2 rows per issue, lane x 16B linear);
// source chunk = slot ^ (row&7); reads swz(row,b)=row*512+(b^((row&7)<<4)).
// Diag tiles: below-diagonal waves skip, transpose waves x2; li==lj -> K=6.
// grid: 256 pos * 10 upper-tri tiles = 2560 blocks (1 block/CU, 10 rounds).
// ---------------------------------------------------------------------------
__device__ __forceinline__ int swzp(int row, int byteoff) {
  return row * 512 + (byteoff ^ ((row & 7) << 4));
}

__global__ __launch_bounds__(512, 2) void k_mmd(const unsigned short* __restrict__ X,
                                                const float* __restrict__ SQP,
                                                float* __restrict__ part) {
  __shared__ unsigned short As[128 * 256];   // 65536 B
  __shared__ unsigned short Bs[128 * 256];   // 65536 B  -> 131072 total

  int bid = blockIdx.x;
  int bx = (bid & 7) * 320 + (bid >> 3);   // XCD swizzle (bijective: 2560 = 8*320)
  int p = bx / 10;
  int tileid = bx - p * 10;
  int it, jt;
  if (tileid < 4)      { it = 0; jt = tileid; }
  else if (tileid < 7) { it = 1; jt = tileid - 3; }
  else if (tileid < 9) { it = 2; jt = tileid - 5; }
  else                 { it = 3; jt = 3; }
  int i0 = it * 128, j0 = jt * 128;
  int t = threadIdx.x;
  int lane = t & 63, w = t >> 6;
  int r = w >> 1, c = w & 1;               // wave subtile: rows [32r..), cols [64c..)
  int l15 = lane & 15, lk = lane >> 4;
  bool diag = (it == jt);
  bool skipw = diag && (c == 0) && (r >= 2);   // strictly below diagonal
  bool dblw  = diag && (c == 1) && (r <= 1);   // transpose of skipped region

  const unsigned short* Xp = X + (size_t)p * (NROW * NCH);
  const char* XA = (const char*)Xp + (size_t)i0 * 512;   // 512 B per row
  const char* XB = (const char*)Xp + (size_t)j0 * 512;

  // ---- stage the FULL K panel, one shot -------------------------------
  int slot  = lane & 31;                   // 16B slot within 512B row
  int rhalf = lane >> 5;                   // lane 0-31 -> row+0, 32-63 -> row+1
#pragma unroll
  for (int j = 0; j < 8; ++j) {
    int row = w * 2 + j * 16 + rhalf;
    int sbyte = ((slot ^ (row & 7)) << 4); // inverse-swizzled source chunk
    const char* ga = XA + (size_t)row * 512 + sbyte;
    const char* gb = XB + (size_t)row * 512 + sbyte;
    __builtin_amdgcn_global_load_lds(
        (const __attribute__((address_space(1))) void*)ga,
        (__attribute__((address_space(3))) void*)((char*)As + w * 1024 + j * 8192), 16, 0, 0);
    __builtin_amdgcn_global_load_lds(
        (const __attribute__((address_space(1))) void*)gb,
        (__attribute__((address_space(3))) void*)((char*)Bs + w * 1024 + j * 8192), 16, 0, 0);
  }

  f32x4 zero = {0.f, 0.f, 0.f, 0.f};
  f32x4 acc[2][4];
#pragma unroll
  for (int m = 0; m < 2; ++m)
#pragma unroll
    for (int n = 0; n < 4; ++n) acc[m][n] = zero;

  __syncthreads();                         // the ONE drain (vmcnt(0)+barrier)

  // ---- barrier-free compute over K=256 --------------------------------
  if (!skipw) {
#pragma unroll
    for (int ks = 0; ks < 8; ++ks) {
      bf16x8 a[2], b[4];
#pragma unroll
      for (int m = 0; m < 2; ++m)
        a[m] = *(const bf16x8*)((const char*)As + swzp(r * 32 + m * 16 + l15, ks * 64 + lk * 16));
#pragma unroll
      for (int n = 0; n < 4; ++n)
        b[n] = *(const bf16x8*)((const char*)Bs + swzp(c * 64 + n * 16 + l15, ks * 64 + lk * 16));
#pragma unroll
      for (int m = 0; m < 2; ++m)
#pragma unroll
        for (int n = 0; n < 4; ++n)
          acc[m][n] = __builtin_amdgcn_mfma_f32_16x16x32_bf16(a[m], b[n], acc[m][n], 0, 0, 0);
    }
  }
  __syncthreads();                         // all reads done; As reusable

  // ---- SQ sums into dead As space -------------------------------------
  float* SQsh = (float*)As;
  if (t < 128) {
    size_t q = (size_t)p * NROW + i0 + t;
    SQsh[t] = SQP[q] + SQP[q + 131072] + SQP[q + 262144] + SQP[q + 393216];
  } else if (t < 256) {
    size_t q = (size_t)p * NROW + j0 + (t - 128);
    SQsh[t] = SQP[q] + SQP[q + 131072] + SQP[q + 262144] + SQP[q + 393216];
  }
  __syncthreads();

  // ---- epilogue: D = sqi + sqj - 2c ; K = sum_b exp(-D/b) -------------
  float lsum = 0.f;
  if (!skipw) {
    const float c80 = 0.01803368801f;  // log2(e)/80
    float sqi[8], sqj[4];
#pragma unroll
    for (int m = 0; m < 2; ++m)
#pragma unroll
      for (int rr = 0; rr < 4; ++rr) sqi[m * 4 + rr] = SQsh[r * 32 + m * 16 + lk * 4 + rr];
#pragma unroll
    for (int n = 0; n < 4; ++n) sqj[n] = SQsh[128 + c * 64 + n * 16 + l15];

#pragma unroll
    for (int m = 0; m < 2; ++m) {
#pragma unroll
      for (int n = 0; n < 4; ++n) {
#pragma unroll
        for (int rr = 0; rr < 4; ++rr) {
          float cv = acc[m][n][rr];
          float D = sqi[m * 4 + rr] + sqj[n] - 2.f * cv;
          float e80 = exp2f(-c80 * D);     // exp(-D/80)
          float e40 = e80 * e80;
          float e20 = e40 * e40;
          float e10 = e20 * e20;
          float e5  = e10 * e10;
          float e2  = e5 * e5 * e10;       // exp(-D/2)
          float K = (e80 + e40) + (e20 + e10) + (e5 + e2);
          if (diag) {
            int li = r * 32 + m * 16 + lk * 4 + rr;
            int lj = c * 64 + n * 16 + l15;
            if (li == lj) K = 6.0f;        // exact diagonal: D==0 -> K=6
          }
          lsum += K;
        }
      }
    }
    if (dblw) lsum *= 2.0f;                // stands in for skipped mirror waves
  }
  // per-wave partial reduce; ALL waves write their slot (skipw writes 0)
#pragma unroll
  for (int off = 32; off; off >>= 1) lsum += __shfl_down(lsum, off, 64);
  if (lane == 0) {
    float sgn = ((it < 2) == (jt < 2)) ? 1.0f : -1.0f;
    float tw  = diag ? 1.0f : 2.0f;        // off-diag tiles count twice (symmetry)
    part[bx * 8 + w] = sgn * tw * lsum;
  }
}

// ---------------------------------------------------------------------------
// Kernel 3: deterministic final reduce of 20480 per-wave partials -> mean
// ---------------------------------------------------------------------------
__global__ __launch_bounds__(256) void k_reduce(const float* __restrict__ part,
                                                float* __restrict__ out) {
  __shared__ float wsum[4];
  int t = threadIdx.x;
  const float4* p4 = (const float4*)part;
  float4 s4 = {0.f, 0.f, 0.f, 0.f};
#pragma unroll
  for (int i = 0; i < 20; ++i) {
    float4 v = p4[i * 256 + t];
    s4.x += v.x; s4.y += v.y; s4.z += v.z; s4.w += v.w;
  }
  float s = (s4.x + s4.y) + (s4.z + s4.w);
#pragma unroll
  for (int off = 32; off; off >>= 1) s += __shfl_down(s, off, 64);
  int lane = t & 63, w = t >> 6;
  if (lane == 0) wsum[w] = s;
  __syncthreads();
  if (t == 0) out[0] = (wsum[0] + wsum[1] + wsum[2] + wsum[3]) * (1.0f / 16777216.0f);
}

extern "C" void kernel_launch(void* const* d_in, const int* in_sizes, int n_in,
                              void* d_out, int out_size, void* d_ws, size_t ws_size,
                              hipStream_t stream) {
  (void)in_sizes; (void)n_in; (void)out_size; (void)ws_size;
  const float* src = (const float*)d_in[0];
  const float* tgt = (const float*)d_in[1];
  char* ws = (char*)d_ws;
  unsigned short* X = (unsigned short*)ws;                    // 67,108,864 B
  float* SQP  = (float*)(ws + 67108864);                      //  2,097,152 B (4 partials)
  float* PART = (float*)(ws + 67108864 + 2097152);            //     81,920 B

  hipLaunchKernelGGL(k_repack, dim3(8192), dim3(256), 0, stream, src, tgt, X, SQP);
  hipLaunchKernelGGL(k_mmd,    dim3(2560), dim3(512), 0, stream, X, SQP, PART);
  hipLaunchKernelGGL(k_reduce, dim3(1),    dim3(256), 0, stream, PART, (float*)d_out);
}

// Round 14
// 80.550 us; speedup vs baseline: 1.2540x; 1.2540x over previous
//
#include <hip/hip_runtime.h>
#include <hip/hip_bf16.h>
#include <stdint.h>

typedef __attribute__((ext_vector_type(8))) short bf16x8;
typedef __attribute__((ext_vector_type(4))) float f32x4;

#define NPOS 256
#define NROW 512
#define NCH  256

// ---------------------------------------------------------------------------
// Kernel 1: repack fp32 [i][c][p] -> bf16 X[p][i][c]  (LDS tile transpose)
// FUSED SQ partials (no atomics): SQP[cb][p][i] = sum_{c in cb} bf16(x)^2.
// r8-proven version (best timed total 80.5).
// grid: 512 i * 4 cb * 4 pb = 8192 blocks, 256 threads.
// ---------------------------------------------------------------------------
__global__ __launch_bounds__(256) void k_repack(const float* __restrict__ src,
                                                const float* __restrict__ tgt,
                                                unsigned short* __restrict__ X,
                                                float* __restrict__ SQP) {
  __shared__ float tile[64 * 65];  // [c][p], +1 pad
  int bx = blockIdx.x;
  int i  = bx >> 4;
  int cb = (bx >> 2) & 3;
  int pb = bx & 3;
  int c0 = cb * 64, p0 = pb * 64;
  const float* base = (i < 256) ? (src + (size_t)i * 65536)
                                : (tgt + (size_t)(i - 256) * 65536);
  int t = threadIdx.x;
#pragma unroll
  for (int it = 0; it < 4; ++it) {
    int idx = it * 256 + t;
    int cl = idx >> 4, pq = idx & 15;                // float4 along p (coalesced)
    float4 v = *(const float4*)&base[(c0 + cl) * 256 + p0 + pq * 4];
    tile[cl * 65 + pq * 4 + 0] = v.x;
    tile[cl * 65 + pq * 4 + 1] = v.y;
    tile[cl * 65 + pq * 4 + 2] = v.z;
    tile[cl * 65 + pq * 4 + 3] = v.w;
  }
  __syncthreads();
#pragma unroll
  for (int it = 0; it < 2; ++it) {
    int idx = it * 256 + t;
    int pl = idx >> 3, c8 = idx & 7;                 // 8 threads per p-row
    unsigned rr[8];
    float part = 0.f;
#pragma unroll
    for (int j = 0; j < 8; ++j) {
      unsigned u = __float_as_uint(tile[(c8 * 8 + j) * 65 + pl]);
      rr[j] = (u + 0x7fffu + ((u >> 16) & 1u)) >> 16;        // RNE to bf16
      float fr = __uint_as_float(rr[j] << 16);               // square ROUNDED value
      part += fr * fr;
    }
    uint4 o = { rr[0] | (rr[1] << 16), rr[2] | (rr[3] << 16),
                rr[4] | (rr[5] << 16), rr[6] | (rr[7] << 16) };
    *(uint4*)&X[((size_t)(p0 + pl) * NROW + i) * NCH + c0 + c8 * 8] = o;
    part += __shfl_xor(part, 1, 64);
    part += __shfl_xor(part, 2, 64);
    part += __shfl_xor(part, 4, 64);
    if (c8 == 0)
      SQP[(size_t)cb * (NPOS * NROW) + (size_t)(p0 + pl) * NROW + i] = part;
  }
}

// ---------------------------------------------------------------------------
// Kernel 2: fused Gram + RBF-sum epilogue, upper-triangle tiles only.
// EXACT r8 structure (best timed): 4 waves (2x2 of 64x64), 128x128 tile,
// BK=64 single buffer, STAGE -> sync -> compute -> sync, epilogue after the
// K loop, SQi/SQj staged up front, launch_bounds (256,4) [VGPR=64, no spill;
// (256,5) spills the accumulator -> r9 disaster]. Staging = global_load_lds
// w=16, linear LDS dest + inverse-swizzled source; reads apply the XOR
// swizzle (conflict-free ONLY at 128-B row pitch -- r13 showed 512-B pitch
// conflicts 3.5M despite identical-looking XOR math).
// grid: 256 pos * 10 tiles = 2560 blocks.
// ---------------------------------------------------------------------------
__device__ __forceinline__ int swz(int row, int byteoff) {
  return row * 128 + (byteoff ^ ((row & 7) << 4));
}

__global__ __launch_bounds__(256, 4) void k_mmd(const unsigned short* __restrict__ X,
                                                const float* __restrict__ SQP,
                                                float* __restrict__ part) {
  __shared__ unsigned short As[128 * 64];
  __shared__ unsigned short Bs[128 * 64];
  __shared__ float SQi[128], SQj[128];
  __shared__ float wsum[4];

  int bid = blockIdx.x;
  int bx = (bid & 7) * 320 + (bid >> 3);   // XCD swizzle (bijective: 2560 = 8*320)
  int p = bx / 10;
  int tileid = bx - p * 10;
  int it, jt;
  if (tileid < 4)      { it = 0; jt = tileid; }
  else if (tileid < 7) { it = 1; jt = tileid - 3; }
  else if (tileid < 9) { it = 2; jt = tileid - 5; }
  else                 { it = 3; jt = 3; }
  int i0 = it * 128, j0 = jt * 128;
  int t = threadIdx.x;
  int lane = t & 63, w = t >> 6;
  int wr = w >> 1, wc = w & 1;
  int l15 = lane & 15, lk = lane >> 4;
  bool diag = (it == jt);
  bool skipw = diag && (w == 2);           // mirror of wave (0,1)
  bool areuse = diag && (wr == wc);        // Gram: B-frags == A-frags

  const unsigned short* Xp = X + (size_t)p * (NROW * NCH);
  const char* XA = (const char*)Xp + (size_t)i0 * 512;   // 512 B per row
  const char* XB = (const char*)Xp + (size_t)j0 * 512;

  if (t < 128) {
    size_t q = (size_t)p * NROW + i0 + t;
    SQi[t] = SQP[q] + SQP[q + 131072] + SQP[q + 262144] + SQP[q + 393216];
  } else {
    size_t q = (size_t)p * NROW + j0 + (t - 128);
    SQj[t - 128] = SQP[q] + SQP[q + 131072] + SQP[q + 262144] + SQP[q + 393216];
  }

  f32x4 zero = {0.f, 0.f, 0.f, 0.f};
  f32x4 acc[4][4];
#pragma unroll
  for (int m = 0; m < 4; ++m)
#pragma unroll
    for (int n = 0; n < 4; ++n) acc[m][n] = zero;

  // per-lane constant source swizzle: row&7 == lane>>3 for every issued chunk
  int lrow = lane >> 3;
  int coff = ((lane & 7) ^ lrow) * 16;

  for (int kk = 0; kk < 4; ++kk) {
#pragma unroll
    for (int s = 0; s < 4; ++s) {
      int rbase = w * 32 + s * 8;          // wave-uniform
      const char* ga = XA + (size_t)(rbase + lrow) * 512 + kk * 128 + coff;
      const char* gb = XB + (size_t)(rbase + lrow) * 512 + kk * 128 + coff;
      __builtin_amdgcn_global_load_lds(
          (const __attribute__((address_space(1))) void*)ga,
          (__attribute__((address_space(3))) void*)((char*)As + rbase * 128), 16, 0, 0);
      __builtin_amdgcn_global_load_lds(
          (const __attribute__((address_space(1))) void*)gb,
          (__attribute__((address_space(3))) void*)((char*)Bs + rbase * 128), 16, 0, 0);
    }
    __syncthreads();                       // drains vmcnt(0): staged data visible
    if (!skipw) {
#pragma unroll
      for (int ks = 0; ks < 2; ++ks) {
        bf16x8 a[4], b[4];
#pragma unroll
        for (int m = 0; m < 4; ++m)
          a[m] = *(const bf16x8*)((const char*)As + swz(wr * 64 + m * 16 + l15, ks * 64 + lk * 16));
        if (areuse) {
#pragma unroll
          for (int n = 0; n < 4; ++n) b[n] = a[n];
        } else {
#pragma unroll
          for (int n = 0; n < 4; ++n)
            b[n] = *(const bf16x8*)((const char*)Bs + swz(wc * 64 + n * 16 + l15, ks * 64 + lk * 16));
        }
#pragma unroll
        for (int m = 0; m < 4; ++m)
#pragma unroll
          for (int n = 0; n < 4; ++n)
            acc[m][n] = __builtin_amdgcn_mfma_f32_16x16x32_bf16(a[m], b[n], acc[m][n], 0, 0, 0);
      }
    }
    __syncthreads();
  }

  // epilogue: D = sqi + sqj - 2c ; K = sum_b exp(-D/b) via 1 exp2 + squarings
  float lsum = 0.f;
  if (!skipw) {
    const float c80 = 0.01803368801f;  // log2(e)/80
    float sqi[16], sqj[4];
#pragma unroll
    for (int m = 0; m < 4; ++m)
#pragma unroll
      for (int r = 0; r < 4; ++r) sqi[m * 4 + r] = SQi[wr * 64 + m * 16 + lk * 4 + r];
#pragma unroll
    for (int n = 0; n < 4; ++n) sqj[n] = SQj[wc * 64 + n * 16 + l15];

    bool sdiag = diag && (wr == wc);
#pragma unroll
    for (int m = 0; m < 4; ++m) {
#pragma unroll
      for (int n = 0; n < 4; ++n) {
#pragma unroll
        for (int r = 0; r < 4; ++r) {
          float cv = acc[m][n][r];
          float D = sqi[m * 4 + r] + sqj[n] - 2.f * cv;
          float e80 = exp2f(-c80 * D);     // exp(-D/80)
          float e40 = e80 * e80;
          float e20 = e40 * e40;
          float e10 = e20 * e20;
          float e5  = e10 * e10;
          float e2  = e5 * e5 * e10;       // exp(-D/2)
          float K = (e80 + e40) + (e20 + e10) + (e5 + e2);
          if (sdiag && m == n) {
            if (lk * 4 + r == l15) K = 6.0f;   // exact diagonal: D==0 -> K=6
          }
          lsum += K;
        }
      }
    }
    if (diag && w == 1) lsum *= 2.0f;      // stands in for skipped mirror wave
  }
#pragma unroll
  for (int off = 32; off; off >>= 1) lsum += __shfl_down(lsum, off, 64);
  if (lane == 0) wsum[w] = lsum;
  __syncthreads();
  if (t == 0) {
    float sgn = ((it < 2) == (jt < 2)) ? 1.0f : -1.0f;
    float tw  = diag ? 1.0f : 2.0f;        // off-diag tiles count twice (symmetry)
    part[bx] = sgn * tw * (wsum[0] + wsum[1] + wsum[2] + wsum[3]);
  }
}

// ---------------------------------------------------------------------------
// Kernel 3: deterministic final reduce of 2560 partials -> mean
// (640 float4 across 256 threads; threads 0-127 take 3 vectors, rest 2)
// ---------------------------------------------------------------------------
__global__ __launch_bounds__(256) void k_reduce(const float* __restrict__ part,
                                                float* __restrict__ out) {
  __shared__ float wsum[4];
  int t = threadIdx.x;
  const float4* p4 = (const float4*)part;
  float4 s4 = {0.f, 0.f, 0.f, 0.f};
#pragma unroll
  for (int i = 0; i < 3; ++i) {
    int idx = i * 256 + t;
    if (idx < 640) {
      float4 v = p4[idx];
      s4.x += v.x; s4.y += v.y; s4.z += v.z; s4.w += v.w;
    }
  }
  float s = (s4.x + s4.y) + (s4.z + s4.w);
#pragma unroll
  for (int off = 32; off; off >>= 1) s += __shfl_down(s, off, 64);
  int lane = t & 63, w = t >> 6;
  if (lane == 0) wsum[w] = s;
  __syncthreads();
  if (t == 0) out[0] = (wsum[0] + wsum[1] + wsum[2] + wsum[3]) * (1.0f / 16777216.0f);
}

extern "C" void kernel_launch(void* const* d_in, const int* in_sizes, int n_in,
                              void* d_out, int out_size, void* d_ws, size_t ws_size,
                              hipStream_t stream) {
  (void)in_sizes; (void)n_in; (void)out_size; (void)ws_size;
  const float* src = (const float*)d_in[0];
  const float* tgt = (const float*)d_in[1];
  char* ws = (char*)d_ws;
  unsigned short* X = (unsigned short*)ws;                    // 67,108,864 B
  float* SQP  = (float*)(ws + 67108864);                      //  2,097,152 B (4 partials)
  float* PART = (float*)(ws + 67108864 + 2097152);            //     10,240 B

  hipLaunchKernelGGL(k_repack, dim3(8192), dim3(256), 0, stream, src, tgt, X, SQP);
  hipLaunchKernelGGL(k_mmd,    dim3(2560), dim3(256), 0, stream, X, SQP, PART);
  hipLaunchKernelGGL(k_reduce, dim3(1),    dim3(256), 0, stream, PART, (float*)d_out);
}

// Round 15
// 80.151 us; speedup vs baseline: 1.2602x; 1.0050x over previous
//
#include <hip/hip_runtime.h>
#include <hip/hip_bf16.h>
#include <stdint.h>

typedef __attribute__((ext_vector_type(4))) float f32x4;

#define NPOS 256
#define NROW 512
#define NCH  256
// fp8 X: 512 rows * 256 ch * 1 B = 131072 B per position panel; 256 B per row.

// ---------------------------------------------------------------------------
// Kernel 1: repack fp32 [i][c][p] -> fp8 e4m3 X[p][i][c] (LDS tile transpose)
// FUSED SQ partials (no atomics): SQP[cb][p][i] = sum_{c in cb} x_f32^2
// (sq from UNQUANTIZED f32 -- cross-term quantization error is then zero-mean
// per pair and cancels under the MMD sign structure; exact diagonal is
// overridden in k_mmd anyway).
// grid: 512 i * 4 cb * 4 pb = 8192 blocks, 256 threads.
// ---------------------------------------------------------------------------
__global__ __launch_bounds__(256) void k_repack(const float* __restrict__ src,
                                                const float* __restrict__ tgt,
                                                unsigned char* __restrict__ X,
                                                float* __restrict__ SQP) {
  __shared__ float tile[64 * 65];  // [c][p], +1 pad
  int bx = blockIdx.x;
  int i  = bx >> 4;
  int cb = (bx >> 2) & 3;
  int pb = bx & 3;
  int c0 = cb * 64, p0 = pb * 64;
  const float* base = (i < 256) ? (src + (size_t)i * 65536)
                                : (tgt + (size_t)(i - 256) * 65536);
  int t = threadIdx.x;
#pragma unroll
  for (int it = 0; it < 4; ++it) {
    int idx = it * 256 + t;
    int cl = idx >> 4, pq = idx & 15;                // float4 along p (coalesced)
    float4 v = *(const float4*)&base[(c0 + cl) * 256 + p0 + pq * 4];
    tile[cl * 65 + pq * 4 + 0] = v.x;
    tile[cl * 65 + pq * 4 + 1] = v.y;
    tile[cl * 65 + pq * 4 + 2] = v.z;
    tile[cl * 65 + pq * 4 + 3] = v.w;
  }
  __syncthreads();
#pragma unroll
  for (int it = 0; it < 2; ++it) {
    int idx = it * 256 + t;
    int pl = idx >> 3, c8 = idx & 7;                 // 8 threads per p-row
    float f[8];
    float part = 0.f;
#pragma unroll
    for (int j = 0; j < 8; ++j) {
      f[j] = tile[(c8 * 8 + j) * 65 + pl];
      part += f[j] * f[j];
    }
    unsigned lo = __builtin_amdgcn_cvt_pk_fp8_f32(f[0], f[1], 0, false);
    lo = (unsigned)__builtin_amdgcn_cvt_pk_fp8_f32(f[2], f[3], (int)lo, true);
    unsigned hi = __builtin_amdgcn_cvt_pk_fp8_f32(f[4], f[5], 0, false);
    hi = (unsigned)__builtin_amdgcn_cvt_pk_fp8_f32(f[6], f[7], (int)hi, true);
    uint2 o = { lo, hi };
    *(uint2*)&X[((size_t)(p0 + pl) * NROW + i) * NCH + c0 + c8 * 8] = o;
    part += __shfl_xor(part, 1, 64);
    part += __shfl_xor(part, 2, 64);
    part += __shfl_xor(part, 4, 64);
    if (c8 == 0)
      SQP[(size_t)cb * (NPOS * NROW) + (size_t)(p0 + pl) * NROW + i] = part;
  }
}

// ---------------------------------------------------------------------------
// Kernel 2: fused Gram + RBF-sum epilogue, upper-triangle tiles, fp8 e4m3.
// EXACT r8/r14 schedule (proven best): 4 waves (2x2 of 64x64), 128x128 tile,
// STAGE -> sync -> compute -> sync, epilogue after K loop, SQi/SQj up front,
// launch_bounds (256,4). fp8 halves bytes everywhere: BK=128 fp8 = 128 B/row
// -> SAME 128-B pitch as the proven conflict-free XOR swizzle, 16 KB/buffer,
// and only TWO vmcnt(0) drains per block instead of four.
// MFMA: mfma_f32_16x16x32_fp8_fp8 (i64 frags; lane row=l&15, k=(l>>4)*8..+8,
// same map family as bf16 16x16x32). grid: 256 pos * 10 tiles = 2560 blocks.
// ---------------------------------------------------------------------------
__device__ __forceinline__ int swzb(int row, int byteoff) {
  // 128-B rows; XOR the 16-B slot bits (4..6) with row&7; bit 3 (8-B half) kept
  return row * 128 + (byteoff ^ ((row & 7) << 4));
}

__global__ __launch_bounds__(256, 4) void k_mmd(const unsigned char* __restrict__ X,
                                                const float* __restrict__ SQP,
                                                float* __restrict__ part) {
  __shared__ unsigned char As[128 * 128];   // 16384 B (128 rows x BK=128 fp8)
  __shared__ unsigned char Bs[128 * 128];   // 16384 B
  __shared__ float SQi[128], SQj[128];
  __shared__ float wsum[4];

  int bid = blockIdx.x;
  int bx = (bid & 7) * 320 + (bid >> 3);   // XCD swizzle (bijective: 2560 = 8*320)
  int p = bx / 10;
  int tileid = bx - p * 10;
  int it, jt;
  if (tileid < 4)      { it = 0; jt = tileid; }
  else if (tileid < 7) { it = 1; jt = tileid - 3; }
  else if (tileid < 9) { it = 2; jt = tileid - 5; }
  else                 { it = 3; jt = 3; }
  int i0 = it * 128, j0 = jt * 128;
  int t = threadIdx.x;
  int lane = t & 63, w = t >> 6;
  int wr = w >> 1, wc = w & 1;
  int l15 = lane & 15, lk = lane >> 4;
  bool diag = (it == jt);
  bool skipw = diag && (w == 2);           // mirror of wave (0,1)
  bool areuse = diag && (wr == wc);        // Gram: B-frags == A-frags

  const unsigned char* Xp = X + (size_t)p * (NROW * NCH);
  const unsigned char* XA = Xp + (size_t)i0 * 256;   // 256 B per row (fp8)
  const unsigned char* XB = Xp + (size_t)j0 * 256;

  if (t < 128) {
    size_t q = (size_t)p * NROW + i0 + t;
    SQi[t] = SQP[q] + SQP[q + 131072] + SQP[q + 262144] + SQP[q + 393216];
  } else {
    size_t q = (size_t)p * NROW + j0 + (t - 128);
    SQj[t - 128] = SQP[q] + SQP[q + 131072] + SQP[q + 262144] + SQP[q + 393216];
  }

  f32x4 zero = {0.f, 0.f, 0.f, 0.f};
  f32x4 acc[4][4];
#pragma unroll
  for (int m = 0; m < 4; ++m)
#pragma unroll
    for (int n = 0; n < 4; ++n) acc[m][n] = zero;

  // staging (per kk): As/Bs = 128 rows x 128 B = 1024 x 16B chunks; 4 per
  // thread per array. Linear LDS dest (wave-uniform base + lane*16) +
  // inverse-swizzled source chunk; row&7 == lane>>3 for every issued chunk.
  int lrow = lane >> 3;
  int coff = ((lane & 7) ^ lrow) * 16;

  for (int kk = 0; kk < 2; ++kk) {
#pragma unroll
    for (int s = 0; s < 4; ++s) {
      int rbase = w * 32 + s * 8;          // wave-uniform
      const unsigned char* ga = XA + (size_t)(rbase + lrow) * 256 + kk * 128 + coff;
      const unsigned char* gb = XB + (size_t)(rbase + lrow) * 256 + kk * 128 + coff;
      __builtin_amdgcn_global_load_lds(
          (const __attribute__((address_space(1))) void*)ga,
          (__attribute__((address_space(3))) void*)((char*)As + rbase * 128), 16, 0, 0);
      __builtin_amdgcn_global_load_lds(
          (const __attribute__((address_space(1))) void*)gb,
          (__attribute__((address_space(3))) void*)((char*)Bs + rbase * 128), 16, 0, 0);
    }
    __syncthreads();                       // drains vmcnt(0): staged data visible
    if (!skipw) {
#pragma unroll
      for (int ks = 0; ks < 4; ++ks) {     // 4 x K=32 slices within BK=128
        long a[4], b[4];
#pragma unroll
        for (int m = 0; m < 4; ++m)
          a[m] = *(const long*)((const char*)As + swzb(wr * 64 + m * 16 + l15, ks * 32 + lk * 8));
        if (areuse) {
#pragma unroll
          for (int n = 0; n < 4; ++n) b[n] = a[n];
        } else {
#pragma unroll
          for (int n = 0; n < 4; ++n)
            b[n] = *(const long*)((const char*)Bs + swzb(wc * 64 + n * 16 + l15, ks * 32 + lk * 8));
        }
#pragma unroll
        for (int m = 0; m < 4; ++m)
#pragma unroll
          for (int n = 0; n < 4; ++n)
            acc[m][n] = __builtin_amdgcn_mfma_f32_16x16x32_fp8_fp8(a[m], b[n], acc[m][n], 0, 0, 0);
      }
    }
    __syncthreads();
  }

  // epilogue: D = sqi + sqj - 2c ; K = sum_b exp(-D/b) via 1 exp2 + squarings
  float lsum = 0.f;
  if (!skipw) {
    const float c80 = 0.01803368801f;  // log2(e)/80
    float sqi[16], sqj[4];
#pragma unroll
    for (int m = 0; m < 4; ++m)
#pragma unroll
      for (int r = 0; r < 4; ++r) sqi[m * 4 + r] = SQi[wr * 64 + m * 16 + lk * 4 + r];
#pragma unroll
    for (int n = 0; n < 4; ++n) sqj[n] = SQj[wc * 64 + n * 16 + l15];

    bool sdiag = diag && (wr == wc);
#pragma unroll
    for (int m = 0; m < 4; ++m) {
#pragma unroll
      for (int n = 0; n < 4; ++n) {
#pragma unroll
        for (int r = 0; r < 4; ++r) {
          float cv = acc[m][n][r];
          float D = sqi[m * 4 + r] + sqj[n] - 2.f * cv;
          float e80 = exp2f(-c80 * D);     // exp(-D/80)
          float e40 = e80 * e80;
          float e20 = e40 * e40;
          float e10 = e20 * e20;
          float e5  = e10 * e10;
          float e2  = e5 * e5 * e10;       // exp(-D/2)
          float K = (e80 + e40) + (e20 + e10) + (e5 + e2);
          if (sdiag && m == n) {
            if (lk * 4 + r == l15) K = 6.0f;   // exact diagonal: D==0 -> K=6
          }
          lsum += K;
        }
      }
    }
    if (diag && w == 1) lsum *= 2.0f;      // stands in for skipped mirror wave
  }
#pragma unroll
  for (int off = 32; off; off >>= 1) lsum += __shfl_down(lsum, off, 64);
  if (lane == 0) wsum[w] = lsum;
  __syncthreads();
  if (t == 0) {
    float sgn = ((it < 2) == (jt < 2)) ? 1.0f : -1.0f;
    float tw  = diag ? 1.0f : 2.0f;        // off-diag tiles count twice (symmetry)
    part[bx] = sgn * tw * (wsum[0] + wsum[1] + wsum[2] + wsum[3]);
  }
}

// ---------------------------------------------------------------------------
// Kernel 3: deterministic final reduce of 2560 partials -> mean
// ---------------------------------------------------------------------------
__global__ __launch_bounds__(256) void k_reduce(const float* __restrict__ part,
                                                float* __restrict__ out) {
  __shared__ float wsum[4];
  int t = threadIdx.x;
  const float4* p4 = (const float4*)part;
  float4 s4 = {0.f, 0.f, 0.f, 0.f};
#pragma unroll
  for (int i = 0; i < 3; ++i) {
    int idx = i * 256 + t;
    if (idx < 640) {
      float4 v = p4[idx];
      s4.x += v.x; s4.y += v.y; s4.z += v.z; s4.w += v.w;
    }
  }
  float s = (s4.x + s4.y) + (s4.z + s4.w);
#pragma unroll
  for (int off = 32; off; off >>= 1) s += __shfl_down(s, off, 64);
  int lane = t & 63, w = t >> 6;
  if (lane == 0) wsum[w] = s;
  __syncthreads();
  if (t == 0) out[0] = (wsum[0] + wsum[1] + wsum[2] + wsum[3]) * (1.0f / 16777216.0f);
}

extern "C" void kernel_launch(void* const* d_in, const int* in_sizes, int n_in,
                              void* d_out, int out_size, void* d_ws, size_t ws_size,
                              hipStream_t stream) {
  (void)in_sizes; (void)n_in; (void)out_size; (void)ws_size;
  const float* src = (const float*)d_in[0];
  const float* tgt = (const float*)d_in[1];
  char* ws = (char*)d_ws;
  unsigned char* X = (unsigned char*)ws;                      // 33,554,432 B (fp8)
  float* SQP  = (float*)(ws + 33554432);                      //  2,097,152 B (4 partials)
  float* PART = (float*)(ws + 33554432 + 2097152);            //     10,240 B

  hipLaunchKernelGGL(k_repack, dim3(8192), dim3(256), 0, stream, src, tgt, X, SQP);
  hipLaunchKernelGGL(k_mmd,    dim3(2560), dim3(256), 0, stream, X, SQP, PART);
  hipLaunchKernelGGL(k_reduce, dim3(1),    dim3(256), 0, stream, PART, (float*)d_out);
}

// Round 16
// 64.012 us; speedup vs baseline: 1.5779x; 1.2521x over previous
//
#include <hip/hip_runtime.h>
#include <hip/hip_bf16.h>
#include <stdint.h>

typedef __attribute__((ext_vector_type(4))) float f32x4;
typedef __attribute__((ext_vector_type(4))) int   i32x4;
typedef __attribute__((ext_vector_type(8))) int   i32x8;

#define NPOS 256
#define NROW 512
#define NCH  256
// fp8 X: 512 rows * 256 ch * 1 B = 131072 B per position panel; 256 B per row.

// ---------------------------------------------------------------------------
// Kernel 1: repack fp32 [i][c][p] -> fp8 e4m3 X[p][i][c] (LDS tile transpose)
// FUSED SQ partials (no atomics), sq from UNQUANTIZED f32. r15-proven
// (absmax 0). grid: 512 i * 4 cb * 4 pb = 8192 blocks, 256 threads.
// ---------------------------------------------------------------------------
__global__ __launch_bounds__(256) void k_repack(const float* __restrict__ src,
                                                const float* __restrict__ tgt,
                                                unsigned char* __restrict__ X,
                                                float* __restrict__ SQP) {
  __shared__ float tile[64 * 65];  // [c][p], +1 pad
  int bx = blockIdx.x;
  int i  = bx >> 4;
  int cb = (bx >> 2) & 3;
  int pb = bx & 3;
  int c0 = cb * 64, p0 = pb * 64;
  const float* base = (i < 256) ? (src + (size_t)i * 65536)
                                : (tgt + (size_t)(i - 256) * 65536);
  int t = threadIdx.x;
#pragma unroll
  for (int it = 0; it < 4; ++it) {
    int idx = it * 256 + t;
    int cl = idx >> 4, pq = idx & 15;                // float4 along p (coalesced)
    float4 v = *(const float4*)&base[(c0 + cl) * 256 + p0 + pq * 4];
    tile[cl * 65 + pq * 4 + 0] = v.x;
    tile[cl * 65 + pq * 4 + 1] = v.y;
    tile[cl * 65 + pq * 4 + 2] = v.z;
    tile[cl * 65 + pq * 4 + 3] = v.w;
  }
  __syncthreads();
#pragma unroll
  for (int it = 0; it < 2; ++it) {
    int idx = it * 256 + t;
    int pl = idx >> 3, c8 = idx & 7;                 // 8 threads per p-row
    float f[8];
    float part = 0.f;
#pragma unroll
    for (int j = 0; j < 8; ++j) {
      f[j] = tile[(c8 * 8 + j) * 65 + pl];
      part += f[j] * f[j];
    }
    unsigned lo = __builtin_amdgcn_cvt_pk_fp8_f32(f[0], f[1], 0, false);
    lo = (unsigned)__builtin_amdgcn_cvt_pk_fp8_f32(f[2], f[3], (int)lo, true);
    unsigned hi = __builtin_amdgcn_cvt_pk_fp8_f32(f[4], f[5], 0, false);
    hi = (unsigned)__builtin_amdgcn_cvt_pk_fp8_f32(f[6], f[7], (int)hi, true);
    uint2 o = { lo, hi };
    *(uint2*)&X[((size_t)(p0 + pl) * NROW + i) * NCH + c0 + c8 * 8] = o;
    part += __shfl_xor(part, 1, 64);
    part += __shfl_xor(part, 2, 64);
    part += __shfl_xor(part, 4, 64);
    if (c8 == 0)
      SQP[(size_t)cb * (NPOS * NROW) + (size_t)(p0 + pl) * NROW + i] = part;
  }
}

// ---------------------------------------------------------------------------
// Kernel 2: fused Gram + RBF-sum epilogue, MX-scaled fp8 (identity scales).
// mfma_scale_f32_16x16x128_f8f6f4: one MFMA consumes K=128 -> per block:
// 32 ds_read_b128 + 32 MFMA + 2 vmcnt(0) drains (vs bf16's 64+64+4).
// Lane's 32-B fragment = 2 adjacent 16-B chunks -> reads use the PROVEN
// 0-conflict slot-XOR pattern (slot=(2lk+h)^(row&7), 128-B pitch).
// Any k-permutation inside the frag cancels (A,B assembled identically);
// C/D layout is shape-determined -> epilogue mapping unchanged.
// Diag tiles: Bs staging skipped entirely (B-frags read from As).
// grid: 256 pos * 10 upper-tri tiles = 2560 blocks, 4 waves (2x2 of 64x64).
// ---------------------------------------------------------------------------
__device__ __forceinline__ int swzb(int row, int byteoff) {
  return row * 128 + (byteoff ^ ((row & 7) << 4));
}

__global__ __launch_bounds__(256, 3) void k_mmd(const unsigned char* __restrict__ X,
                                                const float* __restrict__ SQP,
                                                float* __restrict__ part) {
  __shared__ unsigned char As[128 * 128];   // 16384 B (128 rows x BK=128 fp8)
  __shared__ unsigned char Bs[128 * 128];   // 16384 B
  __shared__ float SQi[128], SQj[128];
  __shared__ float wsum[4];

  int bid = blockIdx.x;
  int bx = (bid & 7) * 320 + (bid >> 3);   // XCD swizzle (bijective: 2560 = 8*320)
  int p = bx / 10;
  int tileid = bx - p * 10;
  int it, jt;
  if (tileid < 4)      { it = 0; jt = tileid; }
  else if (tileid < 7) { it = 1; jt = tileid - 3; }
  else if (tileid < 9) { it = 2; jt = tileid - 5; }
  else                 { it = 3; jt = 3; }
  int i0 = it * 128, j0 = jt * 128;
  int t = threadIdx.x;
  int lane = t & 63, w = t >> 6;
  int wr = w >> 1, wc = w & 1;
  int l15 = lane & 15, lk = lane >> 4;
  bool diag = (it == jt);
  bool skipw = diag && (w == 2);           // mirror of wave (0,1)

  const unsigned char* Xp = X + (size_t)p * (NROW * NCH);
  const unsigned char* XA = Xp + (size_t)i0 * 256;   // 256 B per row (fp8)
  const unsigned char* XB = Xp + (size_t)j0 * 256;

  if (t < 128) {
    size_t q = (size_t)p * NROW + i0 + t;
    SQi[t] = SQP[q] + SQP[q + 131072] + SQP[q + 262144] + SQP[q + 393216];
  } else {
    size_t q = (size_t)p * NROW + j0 + (t - 128);
    SQj[t - 128] = SQP[q] + SQP[q + 131072] + SQP[q + 262144] + SQP[q + 393216];
  }

  f32x4 zero = {0.f, 0.f, 0.f, 0.f};
  f32x4 acc[4][4];
#pragma unroll
  for (int m = 0; m < 4; ++m)
#pragma unroll
    for (int n = 0; n < 4; ++n) acc[m][n] = zero;

  // staging: linear LDS dest (wave-uniform base + lane*16) + inverse-swizzled
  // source chunk; row&7 == lane>>3 for every issued chunk.
  int lrow = lane >> 3;
  int coff = ((lane & 7) ^ lrow) * 16;

  for (int kk = 0; kk < 2; ++kk) {
#pragma unroll
    for (int s = 0; s < 4; ++s) {
      int rbase = w * 32 + s * 8;          // wave-uniform
      const unsigned char* ga = XA + (size_t)(rbase + lrow) * 256 + kk * 128 + coff;
      __builtin_amdgcn_global_load_lds(
          (const __attribute__((address_space(1))) void*)ga,
          (__attribute__((address_space(3))) void*)((char*)As + rbase * 128), 16, 0, 0);
      if (!diag) {                         // diag: B-panel == A-panel, skip Bs
        const unsigned char* gb = XB + (size_t)(rbase + lrow) * 256 + kk * 128 + coff;
        __builtin_amdgcn_global_load_lds(
            (const __attribute__((address_space(1))) void*)gb,
            (__attribute__((address_space(3))) void*)((char*)Bs + rbase * 128), 16, 0, 0);
      }
    }
    __syncthreads();                       // drains vmcnt(0): staged data visible
    if (!skipw) {
      const unsigned char* Bb = diag ? As : Bs;   // diag reads B-frags from As
      i32x8 b[4];
#pragma unroll
      for (int n = 0; n < 4; ++n) {
        int row = wc * 64 + n * 16 + l15;
        i32x4 blo = *(const i32x4*)((const char*)Bb + swzb(row, lk * 32));
        i32x4 bhi = *(const i32x4*)((const char*)Bb + swzb(row, lk * 32 + 16));
        b[n] = __builtin_shufflevector(blo, bhi, 0, 1, 2, 3, 4, 5, 6, 7);
      }
#pragma unroll
      for (int m = 0; m < 4; ++m) {
        int row = wr * 64 + m * 16 + l15;
        i32x4 alo = *(const i32x4*)((const char*)As + swzb(row, lk * 32));
        i32x4 ahi = *(const i32x4*)((const char*)As + swzb(row, lk * 32 + 16));
        i32x8 a = __builtin_shufflevector(alo, ahi, 0, 1, 2, 3, 4, 5, 6, 7);
#pragma unroll
        for (int n = 0; n < 4; ++n)
          acc[m][n] = __builtin_amdgcn_mfma_scale_f32_16x16x128_f8f6f4(
              a, b[n], acc[m][n], 0, 0, 0, 127, 0, 127);  // fp8/fp8, scale=1.0
      }
    }
    __syncthreads();
  }

  // epilogue: D = sqi + sqj - 2c ; K = sum_b exp(-D/b) via 1 exp2 + squarings
  float lsum = 0.f;
  if (!skipw) {
    const float c80 = 0.01803368801f;  // log2(e)/80
    float sqi[16], sqj[4];
#pragma unroll
    for (int m = 0; m < 4; ++m)
#pragma unroll
      for (int r = 0; r < 4; ++r) sqi[m * 4 + r] = SQi[wr * 64 + m * 16 + lk * 4 + r];
#pragma unroll
    for (int n = 0; n < 4; ++n) sqj[n] = SQj[wc * 64 + n * 16 + l15];

    bool sdiag = diag && (wr == wc);
#pragma unroll
    for (int m = 0; m < 4; ++m) {
#pragma unroll
      for (int n = 0; n < 4; ++n) {
#pragma unroll
        for (int r = 0; r < 4; ++r) {
          float cv = acc[m][n][r];
          float D = sqi[m * 4 + r] + sqj[n] - 2.f * cv;
          float e80 = exp2f(-c80 * D);     // exp(-D/80)
          float e40 = e80 * e80;
          float e20 = e40 * e40;
          float e10 = e20 * e20;
          float e5  = e10 * e10;
          float e2  = e5 * e5 * e10;       // exp(-D/2)
          float K = (e80 + e40) + (e20 + e10) + (e5 + e2);
          if (sdiag && m == n) {
            if (lk * 4 + r == l15) K = 6.0f;   // exact diagonal: D==0 -> K=6
          }
          lsum += K;
        }
      }
    }
    if (diag && w == 1) lsum *= 2.0f;      // stands in for skipped mirror wave
  }
#pragma unroll
  for (int off = 32; off; off >>= 1) lsum += __shfl_down(lsum, off, 64);
  if (lane == 0) wsum[w] = lsum;
  __syncthreads();
  if (t == 0) {
    float sgn = ((it < 2) == (jt < 2)) ? 1.0f : -1.0f;
    float tw  = diag ? 1.0f : 2.0f;        // off-diag tiles count twice (symmetry)
    part[bx] = sgn * tw * (wsum[0] + wsum[1] + wsum[2] + wsum[3]);
  }
}

// ---------------------------------------------------------------------------
// Kernel 3: deterministic final reduce of 2560 partials -> mean
// ---------------------------------------------------------------------------
__global__ __launch_bounds__(256) void k_reduce(const float* __restrict__ part,
                                                float* __restrict__ out) {
  __shared__ float wsum[4];
  int t = threadIdx.x;
  const float4* p4 = (const float4*)part;
  float4 s4 = {0.f, 0.f, 0.f, 0.f};
#pragma unroll
  for (int i = 0; i < 3; ++i) {
    int idx = i * 256 + t;
    if (idx < 640) {
      float4 v = p4[idx];
      s4.x += v.x; s4.y += v.y; s4.z += v.z; s4.w += v.w;
    }
  }
  float s = (s4.x + s4.y) + (s4.z + s4.w);
#pragma unroll
  for (int off = 32; off; off >>= 1) s += __shfl_down(s, off, 64);
  int lane = t & 63, w = t >> 6;
  if (lane == 0) wsum[w] = s;
  __syncthreads();
  if (t == 0) out[0] = (wsum[0] + wsum[1] + wsum[2] + wsum[3]) * (1.0f / 16777216.0f);
}

extern "C" void kernel_launch(void* const* d_in, const int* in_sizes, int n_in,
                              void* d_out, int out_size, void* d_ws, size_t ws_size,
                              hipStream_t stream) {
  (void)in_sizes; (void)n_in; (void)out_size; (void)ws_size;
  const float* src = (const float*)d_in[0];
  const float* tgt = (const float*)d_in[1];
  char* ws = (char*)d_ws;
  unsigned char* X = (unsigned char*)ws;                      // 33,554,432 B (fp8)
  float* SQP  = (float*)(ws + 33554432);                      //  2,097,152 B (4 partials)
  float* PART = (float*)(ws + 33554432 + 2097152);            //     10,240 B

  hipLaunchKernelGGL(k_repack, dim3(8192), dim3(256), 0, stream, src, tgt, X, SQP);
  hipLaunchKernelGGL(k_mmd,    dim3(2560), dim3(256), 0, stream, X, SQP, PART);
  hipLaunchKernelGGL(k_reduce, dim3(1),    dim3(256), 0, stream, PART, (float*)d_out);
}